// Round 5
// baseline (19686.539 us; speedup 1.0000x reference)
//
#include <hip/hip_runtime.h>
#include <cstdint>

typedef unsigned long long u64;
typedef unsigned int u32;

#define B_      32
#define CIN_    3
#define NPTS    4096
#define DIM_    256
#define PIECES_ 20

// ---------------------------------------------------------------------------
// Kernel 1: h = W2 @ relu(W1 @ x + b1) + b2, modeling modern np.einsum
// (npyv_muladd = FMA on AVX2 hosts, axpy kernel, contraction index ascending,
// ONE accumulator per output element, bias added afterwards, separately):
//   layer1: s = fl(w0*x0); s = fma(w1,x1,s); s = fma(w2,x2,s); s = fl(s+b1)
//   layer2: acc = fma(W2[o,i], h1[i], acc), i = 0..255 ascending; fl(acc+b2)
// Tile: 128 o x 128 p, K-chunked by 64, 8x8 per-thread register tile.
// ---------------------------------------------------------------------------
#define BP 128
#define BM 128
#define BK 64

__global__ __launch_bounds__(256, 2)
void k_h(const float* __restrict__ x, const float* __restrict__ W1,
         const float* __restrict__ b1, const float* __restrict__ W2,
         const float* __restrict__ b2, float* __restrict__ hout)
{
    __shared__ float xs[CIN_][BP];
    __shared__ __align__(16) float h1s[BK][BP + 4];
    __shared__ __align__(16) float w2s[BK][BM + 4];

    const int t  = threadIdx.x;
    const int pt = blockIdx.x, oc = blockIdx.y, b = blockIdx.z;
    const int p0 = pt * BP, o0 = oc * BM;

    for (int idx = t; idx < CIN_ * BP; idx += 256) {
        int cc = idx / BP, p = idx % BP;
        xs[cc][p] = x[((size_t)b * CIN_ + cc) * NPTS + p0 + p];
    }

    float acc[8][8];
#pragma unroll
    for (int u = 0; u < 8; ++u)
#pragma unroll
        for (int v = 0; v < 8; ++v) acc[u][v] = 0.f;

    const int pa = (t & 15) * 4;
    const int ob = ((t >> 4) & 15) * 4;

    for (int kb = 0; kb < DIM_; kb += BK) {
        __syncthreads();
        // stage h1 chunk: fma chain ascending i, bias last, relu
        {
            int p  = t & 127;
            int i0 = (t >> 7) * 32;
            float x0 = xs[0][p], x1 = xs[1][p], x2 = xs[2][p];
            for (int q = 0; q < 32; ++q) {
                int gi = kb + i0 + q;
                float s = __fmul_rn(W1[gi * 3 + 0], x0);     // fma(w0,x0,0)
                s = __builtin_fmaf(W1[gi * 3 + 1], x1, s);
                s = __builtin_fmaf(W1[gi * 3 + 2], x2, s);
                s = __fadd_rn(s, b1[gi]);                    // bias: separate add
                h1s[i0 + q][p] = s > 0.f ? s : 0.f;
            }
        }
        // stage W2 chunk transposed: w2s[i_local][o_local]
        {
            int cc = t & 63, r0 = t >> 6;
            for (int q = 0; q < 32; ++q) {
                int rr = r0 + q * 4;
                w2s[cc][rr] = W2[(size_t)(o0 + rr) * DIM_ + kb + cc];
            }
        }
        __syncthreads();

#pragma unroll 4
        for (int i = 0; i < BK; ++i) {
            float4 ha = *(const float4*)&h1s[i][pa];
            float4 hb = *(const float4*)&h1s[i][pa + 64];
            float4 wa = *(const float4*)&w2s[i][ob];
            float4 wb = *(const float4*)&w2s[i][ob + 64];
            float hv[8] = {ha.x, ha.y, ha.z, ha.w, hb.x, hb.y, hb.z, hb.w};
            float wv[8] = {wa.x, wa.y, wa.z, wa.w, wb.x, wb.y, wb.z, wb.w};
#pragma unroll
            for (int u = 0; u < 8; ++u)
#pragma unroll
                for (int v = 0; v < 8; ++v)
                    acc[u][v] = __builtin_fmaf(wv[u], hv[v], acc[u][v]);
        }
    }

#pragma unroll
    for (int u = 0; u < 8; ++u) {
        int ol = (u < 4) ? (ob + u) : (ob + 60 + u);
        int og = o0 + ol;
        float bb = b2[og];
        float4 v0 = make_float4(__fadd_rn(acc[u][0], bb), __fadd_rn(acc[u][1], bb),
                                __fadd_rn(acc[u][2], bb), __fadd_rn(acc[u][3], bb));
        float4 v1 = make_float4(__fadd_rn(acc[u][4], bb), __fadd_rn(acc[u][5], bb),
                                __fadd_rn(acc[u][6], bb), __fadd_rn(acc[u][7], bb));
        size_t rowbase = ((size_t)(b * DIM_ + og)) * NPTS + p0;
        *(float4*)&hout[rowbase + pa]      = v0;
        *(float4*)&hout[rowbase + pa + 64] = v1;
    }
}

// ---------------------------------------------------------------------------
// Kernel 2: per (b,c) row -> stable descending argsort + FSPool dot.
// Key: hi32 = ~orderable(hm_f32) (descending hm), lo32 = index (stable ties).
// hm = fl(h + (-99999)) for masked points. Hybrid bitonic (regs/shfl/LDS).
// ---------------------------------------------------------------------------
#define REGPASS(J)                                                        \
    {                                                                     \
        _Pragma("unroll")                                                 \
        for (int s = 0; s < 16; ++s) {                                    \
            if ((s & (J)) == 0) {                                         \
                const int s2 = s | (J);                                   \
                int i   = t * 16 + s;                                     \
                bool up = ((i & k) == 0);                                 \
                u64 a = r[s], bb2 = r[s2];                                \
                bool sw = up ? (a > bb2) : (a < bb2);                     \
                if (sw) { r[s] = bb2; r[s2] = a; }                        \
            }                                                             \
        }                                                                 \
    }

__global__ __launch_bounds__(256, 4)
void k_sortpool(const float* __restrict__ hbuf, const int* __restrict__ n_points,
                const float* __restrict__ pool_w, float* __restrict__ out)
{
    __shared__ u64 lds[4096];
    __shared__ float pw[PIECES_ + 1];
    __shared__ float red[4];

    const int t  = threadIdx.x;
    const int bc = blockIdx.x;          // b*256 + c
    const int c  = bc & 255;

    if (t < PIECES_ + 1) pw[t] = pool_w[c * (PIECES_ + 1) + t];

    const int n  = n_points[bc >> 8];
    const int dn = (n - 1) > 1 ? (n - 1) : 1;
    const float denomf = (float)dn;

    const float* hrow = hbuf + (size_t)bc * NPTS;
    u64 r[16];
#pragma unroll
    for (int s4 = 0; s4 < 4; ++s4) {
        float4 hv = *(const float4*)&hrow[t * 16 + s4 * 4];
        float hvv[4] = {hv.x, hv.y, hv.z, hv.w};
#pragma unroll
        for (int v = 0; v < 4; ++v) {
            int i = t * 16 + s4 * 4 + v;
            float hm = (i <= dn) ? hvv[v] : __fadd_rn(hvv[v], -99999.0f);
            u32 ub = __float_as_uint(hm);
            if ((ub & 0x7FFFFFFFu) == 0) ub = 0;   // canonicalize -0 -> +0
            u32 u  = (ub & 0x80000000u) ? ~ub : (ub ^ 0x80000000u);
            r[s4 * 4 + v] = ((u64)(~u) << 32) | (u32)i;
        }
    }

    for (int k = 2; k <= 4096; k <<= 1) {
        int j = k >> 1;
        // LDS passes (j = 2048, 1024)
        for (; j >= 1024; j >>= 1) {
            int m = j >> 4;
            __syncthreads();
#pragma unroll
            for (int s = 0; s < 16; ++s) lds[s * 256 + t] = r[s];
            __syncthreads();
#pragma unroll
            for (int s = 0; s < 16; ++s) {
                int i = t * 16 + s;
                u64 o = lds[s * 256 + (t ^ m)];
                bool up    = ((i & k) == 0);
                bool lower = ((i & j) == 0);
                u64 mn = r[s] < o ? r[s] : o;
                u64 mx = r[s] < o ? o : r[s];
                r[s] = (lower == up) ? mn : mx;
            }
        }
        // shuffle passes (j = 512..16)
        for (; j >= 16; j >>= 1) {
            int m = j >> 4;
#pragma unroll
            for (int s = 0; s < 16; ++s) {
                int i = t * 16 + s;
                u32 lo = __shfl_xor((u32)r[s], m, 64);
                u32 hi = __shfl_xor((u32)(r[s] >> 32), m, 64);
                u64 o  = ((u64)hi << 32) | lo;
                bool up    = ((i & k) == 0);
                bool lower = ((i & j) == 0);
                u64 mn = r[s] < o ? r[s] : o;
                u64 mx = r[s] < o ? o : r[s];
                r[s] = (lower == up) ? mn : mx;
            }
        }
        // register passes (j = 8,4,2,1)
        switch (j) {
            case 8: REGPASS(8);
            case 4: REGPASS(4);
            case 2: REGPASS(2);
            case 1: REGPASS(1);
            default: break;
        }
    }

    // perm write (over the h row) + pooled partial
    float* permout = out + 8192 + (size_t)bc * NPTS;
    float local = 0.f;
#pragma unroll
    for (int s4 = 0; s4 < 4; ++s4) {
        float pv[4];
#pragma unroll
        for (int v = 0; v < 4; ++v) {
            int i = t * 16 + s4 * 4 + v;
            u64 key = r[s4 * 4 + v];
            pv[v] = (float)(u32)(key & 0xFFFFFFFFu);
            if (i <= dn) {
                u32 u    = ~(u32)(key >> 32);
                u32 bits = (u & 0x80000000u) ? (u ^ 0x80000000u) : ~u;
                float hs = __uint_as_float(bits);
                float ratio = (float)i / denomf;
                float index = 20.0f * ratio;
                int   ii    = (int)index;
                if (ii > PIECES_) ii = PIECES_;
                float frac  = index - (float)ii;
                int   i2    = ii + 1 < PIECES_ ? ii + 1 : PIECES_;
                float w = (1.0f - frac) * pw[ii] + frac * pw[i2];
                local += hs * w;
            }
        }
        float4 pq = make_float4(pv[0], pv[1], pv[2], pv[3]);
        *(float4*)&permout[t * 16 + s4 * 4] = pq;
    }
#pragma unroll
    for (int off = 32; off >= 1; off >>= 1)
        local += __shfl_down(local, (unsigned)off, 64);
    if ((t & 63) == 0) red[t >> 6] = local;
    __syncthreads();
    if (t == 0) out[bc] = red[0] + red[1] + red[2] + red[3];
}

// ---------------------------------------------------------------------------
// Kernel 3: y = relu(pooled @ L1^T + bl1) @ L2^T + bl2, in place over pooled.
// ---------------------------------------------------------------------------
__global__ void k_mlp(const float* __restrict__ L1, const float* __restrict__ bl1,
                      const float* __restrict__ L2, const float* __restrict__ bl2,
                      float* __restrict__ out)
{
    __shared__ float ps[DIM_];
    __shared__ float zs[DIM_];
    const int b = blockIdx.x, t = threadIdx.x;
    ps[t] = out[b * DIM_ + t];
    __syncthreads();
    float a = bl1[t];
    for (int i = 0; i < DIM_; ++i) a += L1[t * DIM_ + i] * ps[i];
    zs[t] = a > 0.f ? a : 0.f;
    __syncthreads();
    float y = bl2[t];
    for (int i = 0; i < DIM_; ++i) y += L2[t * DIM_ + i] * zs[i];
    out[b * DIM_ + t] = y;
}

// ---------------------------------------------------------------------------
extern "C" void kernel_launch(void* const* d_in, const int* in_sizes, int n_in,
                              void* d_out, int out_size, void* d_ws, size_t ws_size,
                              hipStream_t stream)
{
    (void)in_sizes; (void)n_in; (void)d_ws; (void)ws_size; (void)out_size;

    const float* x        = (const float*)d_in[0];
    const int*   n_points = (const int*)  d_in[1];
    const float* W1       = (const float*)d_in[2];
    const float* b1       = (const float*)d_in[3];
    const float* W2       = (const float*)d_in[4];
    const float* b2       = (const float*)d_in[5];
    const float* pool_w   = (const float*)d_in[6];
    const float* L1       = (const float*)d_in[7];
    const float* bl1      = (const float*)d_in[8];
    const float* L2       = (const float*)d_in[9];
    const float* bl2      = (const float*)d_in[10];

    float* out  = (float*)d_out;
    float* hbuf = out + 8192;   // stage h in the perm region

    k_h<<<dim3(NPTS / BP, DIM_ / BM, B_), 256, 0, stream>>>(x, W1, b1, W2, b2, hbuf);
    k_sortpool<<<B_ * DIM_, 256, 0, stream>>>(hbuf, n_points, pool_w, out);
    k_mlp<<<B_, 256, 0, stream>>>(L1, bl1, L2, bl2, out);
}

// Round 6
// 840.295 us; speedup vs baseline: 23.4281x; 23.4281x over previous
//
#include <hip/hip_runtime.h>
#include <cstdint>

typedef unsigned long long u64;
typedef unsigned int u32;

#define B_      32
#define CIN_    3
#define NPTS    4096
#define DIM_    256
#define PIECES_ 20

// ---------------------------------------------------------------------------
// Kernel 1: h = W2 @ relu(W1 @ x + b1) + b2, modeling modern np.einsum
// (npyv_muladd = FMA on AVX2 hosts, axpy kernel, contraction index ascending,
// ONE accumulator per output element, bias added afterwards, separately):
//   layer1: s = fl(w0*x0); s = fma(w1,x1,s); s = fma(w2,x2,s); s = fl(s+b1)
//   layer2: acc = fma(W2[o,i], h1[i], acc), i = 0..255 ascending; fl(acc+b2)
// Tile: 128 o x 128 p, K-chunked by 64, 8x8 per-thread register tile.
// ---------------------------------------------------------------------------
#define BP 128
#define BM 128
#define BK 64

__global__ __launch_bounds__(256, 2)
void k_h(const float* __restrict__ x, const float* __restrict__ W1,
         const float* __restrict__ b1, const float* __restrict__ W2,
         const float* __restrict__ b2, float* __restrict__ hout)
{
    __shared__ float xs[CIN_][BP];
    __shared__ __align__(16) float h1s[BK][BP + 4];
    __shared__ __align__(16) float w2s[BK][BM + 4];

    const int t  = threadIdx.x;
    const int pt = blockIdx.x, oc = blockIdx.y, b = blockIdx.z;
    const int p0 = pt * BP, o0 = oc * BM;

    for (int idx = t; idx < CIN_ * BP; idx += 256) {
        int cc = idx / BP, p = idx % BP;
        xs[cc][p] = x[((size_t)b * CIN_ + cc) * NPTS + p0 + p];
    }

    float acc[8][8];
#pragma unroll
    for (int u = 0; u < 8; ++u)
#pragma unroll
        for (int v = 0; v < 8; ++v) acc[u][v] = 0.f;

    const int pa = (t & 15) * 4;
    const int ob = ((t >> 4) & 15) * 4;

    for (int kb = 0; kb < DIM_; kb += BK) {
        __syncthreads();
        // stage h1 chunk: fma chain ascending i, bias last, relu
        {
            int p  = t & 127;
            int i0 = (t >> 7) * 32;
            float x0 = xs[0][p], x1 = xs[1][p], x2 = xs[2][p];
            for (int q = 0; q < 32; ++q) {
                int gi = kb + i0 + q;
                float s = __fmul_rn(W1[gi * 3 + 0], x0);     // fma(w0,x0,0)
                s = __builtin_fmaf(W1[gi * 3 + 1], x1, s);
                s = __builtin_fmaf(W1[gi * 3 + 2], x2, s);
                s = __fadd_rn(s, b1[gi]);                    // bias: separate add
                h1s[i0 + q][p] = s > 0.f ? s : 0.f;
            }
        }
        // stage W2 chunk transposed: w2s[i_local][o_local]
        {
            int cc = t & 63, r0 = t >> 6;
            for (int q = 0; q < 32; ++q) {
                int rr = r0 + q * 4;
                w2s[cc][rr] = W2[(size_t)(o0 + rr) * DIM_ + kb + cc];
            }
        }
        __syncthreads();

#pragma unroll 4
        for (int i = 0; i < BK; ++i) {
            float4 ha = *(const float4*)&h1s[i][pa];
            float4 hb = *(const float4*)&h1s[i][pa + 64];
            float4 wa = *(const float4*)&w2s[i][ob];
            float4 wb = *(const float4*)&w2s[i][ob + 64];
            float hv[8] = {ha.x, ha.y, ha.z, ha.w, hb.x, hb.y, hb.z, hb.w};
            float wv[8] = {wa.x, wa.y, wa.z, wa.w, wb.x, wb.y, wb.z, wb.w};
#pragma unroll
            for (int u = 0; u < 8; ++u)
#pragma unroll
                for (int v = 0; v < 8; ++v)
                    acc[u][v] = __builtin_fmaf(wv[u], hv[v], acc[u][v]);
        }
    }

#pragma unroll
    for (int u = 0; u < 8; ++u) {
        int ol = (u < 4) ? (ob + u) : (ob + 60 + u);
        int og = o0 + ol;
        float bb = b2[og];
        float4 v0 = make_float4(__fadd_rn(acc[u][0], bb), __fadd_rn(acc[u][1], bb),
                                __fadd_rn(acc[u][2], bb), __fadd_rn(acc[u][3], bb));
        float4 v1 = make_float4(__fadd_rn(acc[u][4], bb), __fadd_rn(acc[u][5], bb),
                                __fadd_rn(acc[u][6], bb), __fadd_rn(acc[u][7], bb));
        size_t rowbase = ((size_t)(b * DIM_ + og)) * NPTS + p0;
        *(float4*)&hout[rowbase + pa]      = v0;
        *(float4*)&hout[rowbase + pa + 64] = v1;
    }
}

// ---------------------------------------------------------------------------
// Kernel 2: per (b,c) row -> stable descending argsort + FSPool dot.
// Key: hi32 = ~orderable(hm_f32) (descending hm), lo32 = index (stable ties).
// hm = fl(h + (-99999)) for masked points. Hybrid bitonic (regs/shfl/LDS).
// NOTE: __launch_bounds__(256, 2) — the (256,4) variant capped VGPRs at 64
// and spilled the entire r[16] state to scratch (34 GB traffic, 19.6 ms).
// ---------------------------------------------------------------------------
#define REGPASS(J)                                                        \
    {                                                                     \
        _Pragma("unroll")                                                 \
        for (int s = 0; s < 16; ++s) {                                    \
            if ((s & (J)) == 0) {                                         \
                const int s2 = s | (J);                                   \
                int i   = t * 16 + s;                                     \
                bool up = ((i & k) == 0);                                 \
                u64 a = r[s], bb2 = r[s2];                                \
                bool sw = up ? (a > bb2) : (a < bb2);                     \
                if (sw) { r[s] = bb2; r[s2] = a; }                        \
            }                                                             \
        }                                                                 \
    }

__global__ __launch_bounds__(256, 2)
void k_sortpool(const float* __restrict__ hbuf, const int* __restrict__ n_points,
                const float* __restrict__ pool_w, float* __restrict__ out)
{
    __shared__ u64 lds[4096];
    __shared__ float pw[PIECES_ + 1];
    __shared__ float red[4];

    const int t  = threadIdx.x;
    const int bc = blockIdx.x;          // b*256 + c
    const int c  = bc & 255;

    if (t < PIECES_ + 1) pw[t] = pool_w[c * (PIECES_ + 1) + t];

    const int n  = n_points[bc >> 8];
    const int dn = (n - 1) > 1 ? (n - 1) : 1;
    const float denomf = (float)dn;

    const float* hrow = hbuf + (size_t)bc * NPTS;
    u64 r[16];
#pragma unroll
    for (int s4 = 0; s4 < 4; ++s4) {
        float4 hv = *(const float4*)&hrow[t * 16 + s4 * 4];
        float hvv[4] = {hv.x, hv.y, hv.z, hv.w};
#pragma unroll
        for (int v = 0; v < 4; ++v) {
            int i = t * 16 + s4 * 4 + v;
            float hm = (i <= dn) ? hvv[v] : __fadd_rn(hvv[v], -99999.0f);
            u32 ub = __float_as_uint(hm);
            if ((ub & 0x7FFFFFFFu) == 0) ub = 0;   // canonicalize -0 -> +0
            u32 u  = (ub & 0x80000000u) ? ~ub : (ub ^ 0x80000000u);
            r[s4 * 4 + v] = ((u64)(~u) << 32) | (u32)i;
        }
    }

    for (int k = 2; k <= 4096; k <<= 1) {
        int j = k >> 1;
        // LDS passes (j = 2048, 1024)
        for (; j >= 1024; j >>= 1) {
            int m = j >> 4;
            __syncthreads();
#pragma unroll
            for (int s = 0; s < 16; ++s) lds[s * 256 + t] = r[s];
            __syncthreads();
#pragma unroll
            for (int s = 0; s < 16; ++s) {
                int i = t * 16 + s;
                u64 o = lds[s * 256 + (t ^ m)];
                bool up    = ((i & k) == 0);
                bool lower = ((i & j) == 0);
                u64 mn = r[s] < o ? r[s] : o;
                u64 mx = r[s] < o ? o : r[s];
                r[s] = (lower == up) ? mn : mx;
            }
        }
        // shuffle passes (j = 512..16)
        for (; j >= 16; j >>= 1) {
            int m = j >> 4;
#pragma unroll
            for (int s = 0; s < 16; ++s) {
                int i = t * 16 + s;
                u32 lo = __shfl_xor((u32)r[s], m, 64);
                u32 hi = __shfl_xor((u32)(r[s] >> 32), m, 64);
                u64 o  = ((u64)hi << 32) | lo;
                bool up    = ((i & k) == 0);
                bool lower = ((i & j) == 0);
                u64 mn = r[s] < o ? r[s] : o;
                u64 mx = r[s] < o ? o : r[s];
                r[s] = (lower == up) ? mn : mx;
            }
        }
        // register passes (j = 8,4,2,1)
        switch (j) {
            case 8: REGPASS(8);
            case 4: REGPASS(4);
            case 2: REGPASS(2);
            case 1: REGPASS(1);
            default: break;
        }
    }

    // perm write (over the h row) + pooled partial
    float* permout = out + 8192 + (size_t)bc * NPTS;
    float local = 0.f;
#pragma unroll
    for (int s4 = 0; s4 < 4; ++s4) {
        float pv[4];
#pragma unroll
        for (int v = 0; v < 4; ++v) {
            int i = t * 16 + s4 * 4 + v;
            u64 key = r[s4 * 4 + v];
            pv[v] = (float)(u32)(key & 0xFFFFFFFFu);
            if (i <= dn) {
                u32 u    = ~(u32)(key >> 32);
                u32 bits = (u & 0x80000000u) ? (u ^ 0x80000000u) : ~u;
                float hs = __uint_as_float(bits);
                float ratio = (float)i / denomf;
                float index = 20.0f * ratio;
                int   ii    = (int)index;
                if (ii > PIECES_) ii = PIECES_;
                float frac  = index - (float)ii;
                int   i2    = ii + 1 < PIECES_ ? ii + 1 : PIECES_;
                float w = (1.0f - frac) * pw[ii] + frac * pw[i2];
                local += hs * w;
            }
        }
        float4 pq = make_float4(pv[0], pv[1], pv[2], pv[3]);
        *(float4*)&permout[t * 16 + s4 * 4] = pq;
    }
#pragma unroll
    for (int off = 32; off >= 1; off >>= 1)
        local += __shfl_down(local, (unsigned)off, 64);
    if ((t & 63) == 0) red[t >> 6] = local;
    __syncthreads();
    if (t == 0) out[bc] = red[0] + red[1] + red[2] + red[3];
}

// ---------------------------------------------------------------------------
// Kernel 3: y = relu(pooled @ L1^T + bl1) @ L2^T + bl2, in place over pooled.
// ---------------------------------------------------------------------------
__global__ void k_mlp(const float* __restrict__ L1, const float* __restrict__ bl1,
                      const float* __restrict__ L2, const float* __restrict__ bl2,
                      float* __restrict__ out)
{
    __shared__ float ps[DIM_];
    __shared__ float zs[DIM_];
    const int b = blockIdx.x, t = threadIdx.x;
    ps[t] = out[b * DIM_ + t];
    __syncthreads();
    float a = bl1[t];
    for (int i = 0; i < DIM_; ++i) a += L1[t * DIM_ + i] * ps[i];
    zs[t] = a > 0.f ? a : 0.f;
    __syncthreads();
    float y = bl2[t];
    for (int i = 0; i < DIM_; ++i) y += L2[t * DIM_ + i] * zs[i];
    out[b * DIM_ + t] = y;
}

// ---------------------------------------------------------------------------
extern "C" void kernel_launch(void* const* d_in, const int* in_sizes, int n_in,
                              void* d_out, int out_size, void* d_ws, size_t ws_size,
                              hipStream_t stream)
{
    (void)in_sizes; (void)n_in; (void)d_ws; (void)ws_size; (void)out_size;

    const float* x        = (const float*)d_in[0];
    const int*   n_points = (const int*)  d_in[1];
    const float* W1       = (const float*)d_in[2];
    const float* b1       = (const float*)d_in[3];
    const float* W2       = (const float*)d_in[4];
    const float* b2       = (const float*)d_in[5];
    const float* pool_w   = (const float*)d_in[6];
    const float* L1       = (const float*)d_in[7];
    const float* bl1      = (const float*)d_in[8];
    const float* L2       = (const float*)d_in[9];
    const float* bl2      = (const float*)d_in[10];

    float* out  = (float*)d_out;
    float* hbuf = out + 8192;   // stage h in the perm region

    k_h<<<dim3(NPTS / BP, DIM_ / BM, B_), 256, 0, stream>>>(x, W1, b1, W2, b2, hbuf);
    k_sortpool<<<B_ * DIM_, 256, 0, stream>>>(hbuf, n_points, pool_w, out);
    k_mlp<<<B_, 256, 0, stream>>>(L1, bl1, L2, bl2, out);
}

// Round 7
// 631.946 us; speedup vs baseline: 31.1523x; 1.3297x over previous
//
#include <hip/hip_runtime.h>
#include <cstdint>

typedef unsigned long long u64;
typedef unsigned int u32;

#define B_      32
#define CIN_    3
#define NPTS    4096
#define DIM_    256
#define PIECES_ 20

// ---------------------------------------------------------------------------
// Kernel 1: h = W2 @ relu(W1 @ x + b1) + b2, modeling modern np.einsum
// (FMA axpy, contraction index ascending, one accumulator, bias added last).
// Verified bit-exact vs the np reference in round 5.
// ---------------------------------------------------------------------------
#define BP 128
#define BM 128
#define BK 64

__global__ __launch_bounds__(256, 2)
void k_h(const float* __restrict__ x, const float* __restrict__ W1,
         const float* __restrict__ b1, const float* __restrict__ W2,
         const float* __restrict__ b2, float* __restrict__ hout)
{
    __shared__ float xs[CIN_][BP];
    __shared__ __align__(16) float h1s[BK][BP + 4];
    __shared__ __align__(16) float w2s[BK][BM + 4];

    const int t  = threadIdx.x;
    const int pt = blockIdx.x, oc = blockIdx.y, b = blockIdx.z;
    const int p0 = pt * BP, o0 = oc * BM;

    for (int idx = t; idx < CIN_ * BP; idx += 256) {
        int cc = idx / BP, p = idx % BP;
        xs[cc][p] = x[((size_t)b * CIN_ + cc) * NPTS + p0 + p];
    }

    float acc[8][8];
#pragma unroll
    for (int u = 0; u < 8; ++u)
#pragma unroll
        for (int v = 0; v < 8; ++v) acc[u][v] = 0.f;

    const int pa = (t & 15) * 4;
    const int ob = ((t >> 4) & 15) * 4;

    for (int kb = 0; kb < DIM_; kb += BK) {
        __syncthreads();
        {
            int p  = t & 127;
            int i0 = (t >> 7) * 32;
            float x0 = xs[0][p], x1 = xs[1][p], x2 = xs[2][p];
            for (int q = 0; q < 32; ++q) {
                int gi = kb + i0 + q;
                float s = __fmul_rn(W1[gi * 3 + 0], x0);
                s = __builtin_fmaf(W1[gi * 3 + 1], x1, s);
                s = __builtin_fmaf(W1[gi * 3 + 2], x2, s);
                s = __fadd_rn(s, b1[gi]);
                h1s[i0 + q][p] = s > 0.f ? s : 0.f;
            }
        }
        {
            int cc = t & 63, r0 = t >> 6;
            for (int q = 0; q < 32; ++q) {
                int rr = r0 + q * 4;
                w2s[cc][rr] = W2[(size_t)(o0 + rr) * DIM_ + kb + cc];
            }
        }
        __syncthreads();

#pragma unroll 4
        for (int i = 0; i < BK; ++i) {
            float4 ha = *(const float4*)&h1s[i][pa];
            float4 hb = *(const float4*)&h1s[i][pa + 64];
            float4 wa = *(const float4*)&w2s[i][ob];
            float4 wb = *(const float4*)&w2s[i][ob + 64];
            float hv[8] = {ha.x, ha.y, ha.z, ha.w, hb.x, hb.y, hb.z, hb.w};
            float wv[8] = {wa.x, wa.y, wa.z, wa.w, wb.x, wb.y, wb.z, wb.w};
#pragma unroll
            for (int u = 0; u < 8; ++u)
#pragma unroll
                for (int v = 0; v < 8; ++v)
                    acc[u][v] = __builtin_fmaf(wv[u], hv[v], acc[u][v]);
        }
    }

#pragma unroll
    for (int u = 0; u < 8; ++u) {
        int ol = (u < 4) ? (ob + u) : (ob + 60 + u);
        int og = o0 + ol;
        float bb = b2[og];
        float4 v0 = make_float4(__fadd_rn(acc[u][0], bb), __fadd_rn(acc[u][1], bb),
                                __fadd_rn(acc[u][2], bb), __fadd_rn(acc[u][3], bb));
        float4 v1 = make_float4(__fadd_rn(acc[u][4], bb), __fadd_rn(acc[u][5], bb),
                                __fadd_rn(acc[u][6], bb), __fadd_rn(acc[u][7], bb));
        size_t rowbase = ((size_t)(b * DIM_ + og)) * NPTS + p0;
        *(float4*)&hout[rowbase + pa]      = v0;
        *(float4*)&hout[rowbase + pa + 64] = v1;
    }
}

// ---------------------------------------------------------------------------
// Kernel 2: per (b,c) row -> stable descending argsort + FSPool dot.
// Same network as round 6 (verified), restructured for minimal VALU:
//  - keys are UNIQUE (idx embedded) so compare-exchange uses the 1-cmp
//    xnor-select form:  r = ((r < o) == wantmin) ? r : o
//  - stages k=2..8: directions compile-time (i&k = s&k)
//  - stage k=16: one uniform bool per thread
//  - stages k>=32: up/lower/wantmin uniform per thread, hoisted per pass;
//    bpermute address computed once per pass (not per element)
// ---------------------------------------------------------------------------
#define CE(SA, SB, ASC)                                                   \
    { u64 _a = r[SA], _b = r[SB];                                         \
      bool _sw = ((_a > _b) == (ASC));                                    \
      if (_sw) { r[SA] = _b; r[SB] = _a; } }

__global__ __launch_bounds__(256, 2)
void k_sortpool(const float* __restrict__ hbuf, const int* __restrict__ n_points,
                const float* __restrict__ pool_w, float* __restrict__ out)
{
    __shared__ u64 lds[4096];
    __shared__ float pw[PIECES_ + 1];
    __shared__ float red[4];

    const int t    = threadIdx.x;
    const int lane = t & 63;
    const int bc   = blockIdx.x;          // b*256 + c
    const int c    = bc & 255;

    if (t < PIECES_ + 1) pw[t] = pool_w[c * (PIECES_ + 1) + t];

    const int n  = n_points[bc >> 8];
    const int dn = (n - 1) > 1 ? (n - 1) : 1;
    const float denomf = (float)dn;

    const float* hrow = hbuf + (size_t)bc * NPTS;
    u64 r[16];
#pragma unroll
    for (int s4 = 0; s4 < 4; ++s4) {
        float4 hv = *(const float4*)&hrow[t * 16 + s4 * 4];
        float hvv[4] = {hv.x, hv.y, hv.z, hv.w};
#pragma unroll
        for (int v = 0; v < 4; ++v) {
            int i = t * 16 + s4 * 4 + v;
            float hm = (i <= dn) ? hvv[v] : __fadd_rn(hvv[v], -99999.0f);
            u32 ub = __float_as_uint(hm);
            if ((ub & 0x7FFFFFFFu) == 0) ub = 0;   // canonicalize -0 -> +0
            u32 u  = (ub & 0x80000000u) ? ~ub : (ub ^ 0x80000000u);
            r[s4 * 4 + v] = ((u64)(~u) << 32) | (u32)i;
        }
    }

    // ---- stages k = 2, 4, 8: fully compile-time (i&k = s&k, i&j = s&j) ----
#pragma unroll
    for (int kk = 1; kk <= 3; ++kk) {
        const int k = 1 << kk;
#pragma unroll
        for (int j = (1 << kk) >> 1; j >= 1; j >>= 1) {
#pragma unroll
            for (int s = 0; s < 16; ++s) {
                if ((s & j) == 0) {
                    const bool asc = ((s & k) == 0);
                    CE(s, s | j, asc)
                }
            }
        }
    }

    // ---- stage k = 16: direction uniform per thread ----
    {
        const bool asc16 = ((t & 1) == 0);
#pragma unroll
        for (int j = 8; j >= 1; j >>= 1)
#pragma unroll
            for (int s = 0; s < 16; ++s)
                if ((s & j) == 0) { CE(s, s | j, asc16) }
    }

    // ---- stages k = 32..4096 ----
    for (int kk = 5; kk <= 12; ++kk) {
        const int k  = 1 << kk;
        const bool up = ((t & (k >> 4)) == 0);
        int j = k >> 1;

        // LDS passes (j = 2048, 1024): partner thread t^(j>>4), same s
        for (; j >= 1024; j >>= 1) {
            const int m = j >> 4;             // 128 or 64
            const bool wantmin = (((t & m) == 0) == up);
            __syncthreads();
#pragma unroll
            for (int s = 0; s < 16; ++s) lds[s * 256 + t] = r[s];
            __syncthreads();
            const int pt2 = t ^ m;
#pragma unroll
            for (int s = 0; s < 16; ++s) {
                u64 o = lds[s * 256 + pt2];
                r[s] = ((r[s] < o) == wantmin) ? r[s] : o;
            }
        }

        // shuffle passes (j = 512..16): partner lane^m within wave64
        for (; j >= 16; j >>= 1) {
            const int m = j >> 4;             // 32..1
            const bool wantmin = (((t & m) == 0) == up);
            const int ba = (lane ^ m) << 2;   // bpermute byte addr, once/pass
#pragma unroll
            for (int s = 0; s < 16; ++s) {
                u32 alo = (u32)r[s], ahi = (u32)(r[s] >> 32);
                u32 olo = (u32)__builtin_amdgcn_ds_bpermute(ba, (int)alo);
                u32 ohi = (u32)__builtin_amdgcn_ds_bpermute(ba, (int)ahi);
                u64 o = ((u64)ohi << 32) | olo;
                r[s] = ((r[s] < o) == wantmin) ? r[s] : o;
            }
        }

        // register passes (j = 8..1): direction uniform = up
#pragma unroll
        for (int j2 = 8; j2 >= 1; j2 >>= 1)
#pragma unroll
            for (int s = 0; s < 16; ++s)
                if ((s & j2) == 0) { CE(s, s | j2, up) }
    }

    // ---- perm write (over the h row) + pooled partial ----
    float* permout = out + 8192 + (size_t)bc * NPTS;
    float local = 0.f;
#pragma unroll
    for (int s4 = 0; s4 < 4; ++s4) {
        float pv[4];
#pragma unroll
        for (int v = 0; v < 4; ++v) {
            int i = t * 16 + s4 * 4 + v;
            u64 key = r[s4 * 4 + v];
            pv[v] = (float)(u32)(key & 0xFFFFFFFFu);
            if (i <= dn) {
                u32 u    = ~(u32)(key >> 32);
                u32 bits = (u & 0x80000000u) ? (u ^ 0x80000000u) : ~u;
                float hs = __uint_as_float(bits);
                float ratio = (float)i / denomf;
                float index = 20.0f * ratio;
                int   ii    = (int)index;
                if (ii > PIECES_) ii = PIECES_;
                float frac  = index - (float)ii;
                int   i2    = ii + 1 < PIECES_ ? ii + 1 : PIECES_;
                float w = (1.0f - frac) * pw[ii] + frac * pw[i2];
                local += hs * w;
            }
        }
        float4 pq = make_float4(pv[0], pv[1], pv[2], pv[3]);
        *(float4*)&permout[t * 16 + s4 * 4] = pq;
    }
#pragma unroll
    for (int off = 32; off >= 1; off >>= 1)
        local += __shfl_down(local, (unsigned)off, 64);
    if ((t & 63) == 0) red[t >> 6] = local;
    __syncthreads();
    if (t == 0) out[bc] = red[0] + red[1] + red[2] + red[3];
}

// ---------------------------------------------------------------------------
// Kernel 3: y = relu(pooled @ L1^T + bl1) @ L2^T + bl2, in place over pooled.
// ---------------------------------------------------------------------------
__global__ void k_mlp(const float* __restrict__ L1, const float* __restrict__ bl1,
                      const float* __restrict__ L2, const float* __restrict__ bl2,
                      float* __restrict__ out)
{
    __shared__ float ps[DIM_];
    __shared__ float zs[DIM_];
    const int b = blockIdx.x, t = threadIdx.x;
    ps[t] = out[b * DIM_ + t];
    __syncthreads();
    float a = bl1[t];
    for (int i = 0; i < DIM_; ++i) a += L1[t * DIM_ + i] * ps[i];
    zs[t] = a > 0.f ? a : 0.f;
    __syncthreads();
    float y = bl2[t];
    for (int i = 0; i < DIM_; ++i) y += L2[t * DIM_ + i] * zs[i];
    out[b * DIM_ + t] = y;
}

// ---------------------------------------------------------------------------
extern "C" void kernel_launch(void* const* d_in, const int* in_sizes, int n_in,
                              void* d_out, int out_size, void* d_ws, size_t ws_size,
                              hipStream_t stream)
{
    (void)in_sizes; (void)n_in; (void)d_ws; (void)ws_size; (void)out_size;

    const float* x        = (const float*)d_in[0];
    const int*   n_points = (const int*)  d_in[1];
    const float* W1       = (const float*)d_in[2];
    const float* b1       = (const float*)d_in[3];
    const float* W2       = (const float*)d_in[4];
    const float* b2       = (const float*)d_in[5];
    const float* pool_w   = (const float*)d_in[6];
    const float* L1       = (const float*)d_in[7];
    const float* bl1      = (const float*)d_in[8];
    const float* L2       = (const float*)d_in[9];
    const float* bl2      = (const float*)d_in[10];

    float* out  = (float*)d_out;
    float* hbuf = out + 8192;   // stage h in the perm region

    k_h<<<dim3(NPTS / BP, DIM_ / BM, B_), 256, 0, stream>>>(x, W1, b1, W2, b2, hbuf);
    k_sortpool<<<B_ * DIM_, 256, 0, stream>>>(hbuf, n_points, pool_w, out);
    k_mlp<<<B_, 256, 0, stream>>>(L1, bl1, L2, bl2, out);
}

// Round 8
// 493.375 us; speedup vs baseline: 39.9018x; 1.2809x over previous
//
#include <hip/hip_runtime.h>
#include <cstdint>

typedef unsigned long long u64;
typedef unsigned int u32;

#define B_      32
#define CIN_    3
#define NPTS    4096
#define DIM_    256
#define PIECES_ 20

// ---------------------------------------------------------------------------
// Kernel 1: h = W2 @ relu(W1 @ x + b1) + b2, modeling modern np.einsum
// (FMA axpy, contraction index ascending, one accumulator, bias added last).
// Verified bit-exact vs the np reference in rounds 5-7.
// ---------------------------------------------------------------------------
#define BP 128
#define BM 128
#define BK 64

__global__ __launch_bounds__(256, 2)
void k_h(const float* __restrict__ x, const float* __restrict__ W1,
         const float* __restrict__ b1, const float* __restrict__ W2,
         const float* __restrict__ b2, float* __restrict__ hout)
{
    __shared__ float xs[CIN_][BP];
    __shared__ __align__(16) float h1s[BK][BP + 4];
    __shared__ __align__(16) float w2s[BK][BM + 4];

    const int t  = threadIdx.x;
    const int pt = blockIdx.x, oc = blockIdx.y, b = blockIdx.z;
    const int p0 = pt * BP, o0 = oc * BM;

    for (int idx = t; idx < CIN_ * BP; idx += 256) {
        int cc = idx / BP, p = idx % BP;
        xs[cc][p] = x[((size_t)b * CIN_ + cc) * NPTS + p0 + p];
    }

    float acc[8][8];
#pragma unroll
    for (int u = 0; u < 8; ++u)
#pragma unroll
        for (int v = 0; v < 8; ++v) acc[u][v] = 0.f;

    const int pa = (t & 15) * 4;
    const int ob = ((t >> 4) & 15) * 4;

    for (int kb = 0; kb < DIM_; kb += BK) {
        __syncthreads();
        {
            int p  = t & 127;
            int i0 = (t >> 7) * 32;
            float x0 = xs[0][p], x1 = xs[1][p], x2 = xs[2][p];
            for (int q = 0; q < 32; ++q) {
                int gi = kb + i0 + q;
                float s = __fmul_rn(W1[gi * 3 + 0], x0);
                s = __builtin_fmaf(W1[gi * 3 + 1], x1, s);
                s = __builtin_fmaf(W1[gi * 3 + 2], x2, s);
                s = __fadd_rn(s, b1[gi]);
                h1s[i0 + q][p] = s > 0.f ? s : 0.f;
            }
        }
        {
            int cc = t & 63, r0 = t >> 6;
            for (int q = 0; q < 32; ++q) {
                int rr = r0 + q * 4;
                w2s[cc][rr] = W2[(size_t)(o0 + rr) * DIM_ + kb + cc];
            }
        }
        __syncthreads();

#pragma unroll 4
        for (int i = 0; i < BK; ++i) {
            float4 ha = *(const float4*)&h1s[i][pa];
            float4 hb = *(const float4*)&h1s[i][pa + 64];
            float4 wa = *(const float4*)&w2s[i][ob];
            float4 wb = *(const float4*)&w2s[i][ob + 64];
            float hv[8] = {ha.x, ha.y, ha.z, ha.w, hb.x, hb.y, hb.z, hb.w};
            float wv[8] = {wa.x, wa.y, wa.z, wa.w, wb.x, wb.y, wb.z, wb.w};
#pragma unroll
            for (int u = 0; u < 8; ++u)
#pragma unroll
                for (int v = 0; v < 8; ++v)
                    acc[u][v] = __builtin_fmaf(wv[u], hv[v], acc[u][v]);
        }
    }

#pragma unroll
    for (int u = 0; u < 8; ++u) {
        int ol = (u < 4) ? (ob + u) : (ob + 60 + u);
        int og = o0 + ol;
        float bb = b2[og];
        float4 v0 = make_float4(__fadd_rn(acc[u][0], bb), __fadd_rn(acc[u][1], bb),
                                __fadd_rn(acc[u][2], bb), __fadd_rn(acc[u][3], bb));
        float4 v1 = make_float4(__fadd_rn(acc[u][4], bb), __fadd_rn(acc[u][5], bb),
                                __fadd_rn(acc[u][6], bb), __fadd_rn(acc[u][7], bb));
        size_t rowbase = ((size_t)(b * DIM_ + og)) * NPTS + p0;
        *(float4*)&hout[rowbase + pa]      = v0;
        *(float4*)&hout[rowbase + pa + 64] = v1;
    }
}

// ---------------------------------------------------------------------------
// Kernel 2: per (b,c) row -> stable descending argsort + FSPool dot.
// Round-7 network (verified), with cross-lane exchanges moved off the DS
// pipe where a DPP lane-permute exists:
//   lane^1 -> quad_perm[1,0,3,2]   (j=16)
//   lane^2 -> quad_perm[2,3,0,1]   (j=32)
//   lane^8 -> row_ror:8            (j=128)
//   lane^{4,16,32} -> ds_bpermute  (j=64,256,512)
//   thread^{64,128} -> LDS         (j=1024,2048)
// ---------------------------------------------------------------------------
#define CE(SA, SB, ASC)                                                   \
    { u64 _a = r[SA], _b = r[SB];                                         \
      bool _sw = ((_a > _b) == (ASC));                                    \
      if (_sw) { r[SA] = _b; r[SB] = _a; } }

template<int CTRL>
__device__ __forceinline__ u64 dpp_xor(u64 v)
{
    u32 lo = (u32)v, hi = (u32)(v >> 32);
    u32 olo = (u32)__builtin_amdgcn_update_dpp(0, (int)lo, CTRL, 0xf, 0xf, true);
    u32 ohi = (u32)__builtin_amdgcn_update_dpp(0, (int)hi, CTRL, 0xf, 0xf, true);
    return ((u64)ohi << 32) | olo;
}

template<int K, int J>
__device__ __forceinline__ void cross_pass(u64 (&r)[16], const int t, const int lane,
                                           u64* lds, const bool up)
{
    if constexpr (J >= 1024) {
        const int m = J >> 4;                    // 64 or 128: cross-wave
        const bool wantmin = (((t & m) == 0) == up);
        __syncthreads();
#pragma unroll
        for (int s = 0; s < 16; ++s) lds[s * 256 + t] = r[s];
        __syncthreads();
        const int pt2 = t ^ m;
#pragma unroll
        for (int s = 0; s < 16; ++s) {
            u64 o = lds[s * 256 + pt2];
            r[s] = ((r[s] < o) == wantmin) ? r[s] : o;
        }
    } else if constexpr (J == 512 || J == 256 || J == 64) {
        const int m = J >> 4;                    // 32, 16, 4: bpermute
        const bool wantmin = (((t & m) == 0) == up);
        const int ba = (lane ^ m) << 2;
#pragma unroll
        for (int s = 0; s < 16; ++s) {
            u32 alo = (u32)r[s], ahi = (u32)(r[s] >> 32);
            u32 olo = (u32)__builtin_amdgcn_ds_bpermute(ba, (int)alo);
            u32 ohi = (u32)__builtin_amdgcn_ds_bpermute(ba, (int)ahi);
            u64 o = ((u64)ohi << 32) | olo;
            r[s] = ((r[s] < o) == wantmin) ? r[s] : o;
        }
    } else {
        constexpr int m    = J >> 4;             // 8, 2, 1: DPP
        constexpr int ctrl = (m == 8) ? 0x128 : (m == 2 ? 0x4E : 0xB1);
        const bool wantmin = (((t & m) == 0) == up);
#pragma unroll
        for (int s = 0; s < 16; ++s) {
            u64 o = dpp_xor<ctrl>(r[s]);
            r[s] = ((r[s] < o) == wantmin) ? r[s] : o;
        }
    }
}

template<int K>
__device__ __forceinline__ void bigstage(u64 (&r)[16], const int t, const int lane, u64* lds)
{
    const bool up = ((t & (K >> 4)) == 0);
    if constexpr (K >= 4096) cross_pass<K, 2048>(r, t, lane, lds, up);
    if constexpr (K >= 2048) cross_pass<K, 1024>(r, t, lane, lds, up);
    if constexpr (K >= 1024) cross_pass<K, 512>(r, t, lane, lds, up);
    if constexpr (K >= 512)  cross_pass<K, 256>(r, t, lane, lds, up);
    if constexpr (K >= 256)  cross_pass<K, 128>(r, t, lane, lds, up);
    if constexpr (K >= 128)  cross_pass<K, 64>(r, t, lane, lds, up);
    if constexpr (K >= 64)   cross_pass<K, 32>(r, t, lane, lds, up);
    cross_pass<K, 16>(r, t, lane, lds, up);
#pragma unroll
    for (int j2 = 8; j2 >= 1; j2 >>= 1)
#pragma unroll
        for (int s = 0; s < 16; ++s)
            if ((s & j2) == 0) { CE(s, s | j2, up) }
}

__global__ __launch_bounds__(256, 2)
void k_sortpool(const float* __restrict__ hbuf, const int* __restrict__ n_points,
                const float* __restrict__ pool_w, float* __restrict__ out)
{
    __shared__ u64 lds[4096];
    __shared__ float pw[PIECES_ + 1];
    __shared__ float red[4];

    const int t    = threadIdx.x;
    const int lane = t & 63;
    const int bc   = blockIdx.x;          // b*256 + c
    const int c    = bc & 255;

    if (t < PIECES_ + 1) pw[t] = pool_w[c * (PIECES_ + 1) + t];

    const int n  = n_points[bc >> 8];
    const int dn = (n - 1) > 1 ? (n - 1) : 1;
    const float denomf = (float)dn;

    const float* hrow = hbuf + (size_t)bc * NPTS;
    u64 r[16];
#pragma unroll
    for (int s4 = 0; s4 < 4; ++s4) {
        float4 hv = *(const float4*)&hrow[t * 16 + s4 * 4];
        float hvv[4] = {hv.x, hv.y, hv.z, hv.w};
#pragma unroll
        for (int v = 0; v < 4; ++v) {
            int i = t * 16 + s4 * 4 + v;
            float hm = (i <= dn) ? hvv[v] : __fadd_rn(hvv[v], -99999.0f);
            u32 ub = __float_as_uint(hm);
            if ((ub & 0x7FFFFFFFu) == 0) ub = 0;   // canonicalize -0 -> +0
            u32 u  = (ub & 0x80000000u) ? ~ub : (ub ^ 0x80000000u);
            r[s4 * 4 + v] = ((u64)(~u) << 32) | (u32)i;
        }
    }

    // ---- stages k = 2, 4, 8: fully compile-time ----
#pragma unroll
    for (int kk = 1; kk <= 3; ++kk) {
        const int k = 1 << kk;
#pragma unroll
        for (int j = (1 << kk) >> 1; j >= 1; j >>= 1) {
#pragma unroll
            for (int s = 0; s < 16; ++s) {
                if ((s & j) == 0) {
                    const bool asc = ((s & k) == 0);
                    CE(s, s | j, asc)
                }
            }
        }
    }

    // ---- stage k = 16: direction uniform per thread ----
    {
        const bool asc16 = ((t & 1) == 0);
#pragma unroll
        for (int j = 8; j >= 1; j >>= 1)
#pragma unroll
            for (int s = 0; s < 16; ++s)
                if ((s & j) == 0) { CE(s, s | j, asc16) }
    }

    // ---- stages k = 32..4096 ----
    bigstage<32>(r, t, lane, lds);
    bigstage<64>(r, t, lane, lds);
    bigstage<128>(r, t, lane, lds);
    bigstage<256>(r, t, lane, lds);
    bigstage<512>(r, t, lane, lds);
    bigstage<1024>(r, t, lane, lds);
    bigstage<2048>(r, t, lane, lds);
    bigstage<4096>(r, t, lane, lds);

    // ---- perm write (over the h row) + pooled partial ----
    float* permout = out + 8192 + (size_t)bc * NPTS;
    float local = 0.f;
#pragma unroll
    for (int s4 = 0; s4 < 4; ++s4) {
        float pv[4];
#pragma unroll
        for (int v = 0; v < 4; ++v) {
            int i = t * 16 + s4 * 4 + v;
            u64 key = r[s4 * 4 + v];
            pv[v] = (float)(u32)(key & 0xFFFFFFFFu);
            if (i <= dn) {
                u32 u    = ~(u32)(key >> 32);
                u32 bits = (u & 0x80000000u) ? (u ^ 0x80000000u) : ~u;
                float hs = __uint_as_float(bits);
                float ratio = (float)i / denomf;
                float index = 20.0f * ratio;
                int   ii    = (int)index;
                if (ii > PIECES_) ii = PIECES_;
                float frac  = index - (float)ii;
                int   i2    = ii + 1 < PIECES_ ? ii + 1 : PIECES_;
                float w = (1.0f - frac) * pw[ii] + frac * pw[i2];
                local += hs * w;
            }
        }
        float4 pq = make_float4(pv[0], pv[1], pv[2], pv[3]);
        *(float4*)&permout[t * 16 + s4 * 4] = pq;
    }
#pragma unroll
    for (int off = 32; off >= 1; off >>= 1)
        local += __shfl_down(local, (unsigned)off, 64);
    if ((t & 63) == 0) red[t >> 6] = local;
    __syncthreads();
    if (t == 0) out[bc] = red[0] + red[1] + red[2] + red[3];
}

// ---------------------------------------------------------------------------
// Kernel 3: y = relu(pooled @ L1^T + bl1) @ L2^T + bl2, in place over pooled.
// ---------------------------------------------------------------------------
__global__ void k_mlp(const float* __restrict__ L1, const float* __restrict__ bl1,
                      const float* __restrict__ L2, const float* __restrict__ bl2,
                      float* __restrict__ out)
{
    __shared__ float ps[DIM_];
    __shared__ float zs[DIM_];
    const int b = blockIdx.x, t = threadIdx.x;
    ps[t] = out[b * DIM_ + t];
    __syncthreads();
    float a = bl1[t];
    for (int i = 0; i < DIM_; ++i) a += L1[t * DIM_ + i] * ps[i];
    zs[t] = a > 0.f ? a : 0.f;
    __syncthreads();
    float y = bl2[t];
    for (int i = 0; i < DIM_; ++i) y += L2[t * DIM_ + i] * zs[i];
    out[b * DIM_ + t] = y;
}

// ---------------------------------------------------------------------------
extern "C" void kernel_launch(void* const* d_in, const int* in_sizes, int n_in,
                              void* d_out, int out_size, void* d_ws, size_t ws_size,
                              hipStream_t stream)
{
    (void)in_sizes; (void)n_in; (void)d_ws; (void)ws_size; (void)out_size;

    const float* x        = (const float*)d_in[0];
    const int*   n_points = (const int*)  d_in[1];
    const float* W1       = (const float*)d_in[2];
    const float* b1       = (const float*)d_in[3];
    const float* W2       = (const float*)d_in[4];
    const float* b2       = (const float*)d_in[5];
    const float* pool_w   = (const float*)d_in[6];
    const float* L1       = (const float*)d_in[7];
    const float* bl1      = (const float*)d_in[8];
    const float* L2       = (const float*)d_in[9];
    const float* bl2      = (const float*)d_in[10];

    float* out  = (float*)d_out;
    float* hbuf = out + 8192;   // stage h in the perm region

    k_h<<<dim3(NPTS / BP, DIM_ / BM, B_), 256, 0, stream>>>(x, W1, b1, W2, b2, hbuf);
    k_sortpool<<<B_ * DIM_, 256, 0, stream>>>(hbuf, n_points, pool_w, out);
    k_mlp<<<B_, 256, 0, stream>>>(L1, bl1, L2, bl2, out);
}

// Round 9
// 488.562 us; speedup vs baseline: 40.2949x; 1.0099x over previous
//
#include <hip/hip_runtime.h>
#include <cstdint>

typedef unsigned long long u64;
typedef unsigned int u32;

#define B_      32
#define CIN_    3
#define NPTS    4096
#define DIM_    256
#define PIECES_ 20

// ---------------------------------------------------------------------------
// Kernel 1: h = W2 @ relu(W1 @ x + b1) + b2, modeling modern np.einsum
// (FMA axpy, contraction index ascending, one accumulator, bias added last).
// Verified bit-exact vs the np reference in rounds 5-8.
// W1/b1 preloaded to LDS once (was: 512 per-thread global loads across chunks).
// ---------------------------------------------------------------------------
#define BP 128
#define BM 128
#define BK 64

__global__ __launch_bounds__(256, 2)
void k_h(const float* __restrict__ x, const float* __restrict__ W1,
         const float* __restrict__ b1, const float* __restrict__ W2,
         const float* __restrict__ b2, float* __restrict__ hout)
{
    __shared__ float xs[CIN_][BP];
    __shared__ __align__(16) float h1s[BK][BP + 4];
    __shared__ __align__(16) float w2s[BK][BM + 4];
    __shared__ float4 w1s[DIM_];    // .xyz = W1 row, .w = b1

    const int t  = threadIdx.x;
    const int pt = blockIdx.x, oc = blockIdx.y, b = blockIdx.z;
    const int p0 = pt * BP, o0 = oc * BM;

    w1s[t] = make_float4(W1[t * 3 + 0], W1[t * 3 + 1], W1[t * 3 + 2], b1[t]);

    for (int idx = t; idx < CIN_ * BP; idx += 256) {
        int cc = idx / BP, p = idx % BP;
        xs[cc][p] = x[((size_t)b * CIN_ + cc) * NPTS + p0 + p];
    }

    float acc[8][8];
#pragma unroll
    for (int u = 0; u < 8; ++u)
#pragma unroll
        for (int v = 0; v < 8; ++v) acc[u][v] = 0.f;

    const int pa = (t & 15) * 4;
    const int ob = ((t >> 4) & 15) * 4;

    for (int kb = 0; kb < DIM_; kb += BK) {
        __syncthreads();
        // stage h1 chunk: fma chain ascending i, bias last, relu
        {
            int p  = t & 127;
            int i0 = (t >> 7) * 32;
            float x0 = xs[0][p], x1 = xs[1][p], x2 = xs[2][p];
            for (int q = 0; q < 32; ++q) {
                float4 wq = w1s[kb + i0 + q];   // broadcast ds_read_b128
                float s = __fmul_rn(wq.x, x0);
                s = __builtin_fmaf(wq.y, x1, s);
                s = __builtin_fmaf(wq.z, x2, s);
                s = __fadd_rn(s, wq.w);
                h1s[i0 + q][p] = s > 0.f ? s : 0.f;
            }
        }
        // stage W2 chunk transposed: w2s[i_local][o_local]
        {
            int cc = t & 63, r0 = t >> 6;
            for (int q = 0; q < 32; ++q) {
                int rr = r0 + q * 4;
                w2s[cc][rr] = W2[(size_t)(o0 + rr) * DIM_ + kb + cc];
            }
        }
        __syncthreads();

#pragma unroll 4
        for (int i = 0; i < BK; ++i) {
            float4 ha = *(const float4*)&h1s[i][pa];
            float4 hb = *(const float4*)&h1s[i][pa + 64];
            float4 wa = *(const float4*)&w2s[i][ob];
            float4 wb = *(const float4*)&w2s[i][ob + 64];
            float hv[8] = {ha.x, ha.y, ha.z, ha.w, hb.x, hb.y, hb.z, hb.w};
            float wv[8] = {wa.x, wa.y, wa.z, wa.w, wb.x, wb.y, wb.z, wb.w};
#pragma unroll
            for (int u = 0; u < 8; ++u)
#pragma unroll
                for (int v = 0; v < 8; ++v)
                    acc[u][v] = __builtin_fmaf(wv[u], hv[v], acc[u][v]);
        }
    }

#pragma unroll
    for (int u = 0; u < 8; ++u) {
        int ol = (u < 4) ? (ob + u) : (ob + 60 + u);
        int og = o0 + ol;
        float bb = b2[og];
        float4 v0 = make_float4(__fadd_rn(acc[u][0], bb), __fadd_rn(acc[u][1], bb),
                                __fadd_rn(acc[u][2], bb), __fadd_rn(acc[u][3], bb));
        float4 v1 = make_float4(__fadd_rn(acc[u][4], bb), __fadd_rn(acc[u][5], bb),
                                __fadd_rn(acc[u][6], bb), __fadd_rn(acc[u][7], bb));
        size_t rowbase = ((size_t)(b * DIM_ + og)) * NPTS + p0;
        *(float4*)&hout[rowbase + pa]      = v0;
        *(float4*)&hout[rowbase + pa + 64] = v1;
    }
}

// ---------------------------------------------------------------------------
// Kernel 2: per (b,c) row -> stable descending argsort + FSPool dot.
// Round-8 network (verified); DPP exchanges now via mov_dpp (undef old
// operand -> single v_mov_b32_dpp, no zero-init mov).
//   lane^1 -> quad_perm[1,0,3,2]   (j=16)
//   lane^2 -> quad_perm[2,3,0,1]   (j=32)
//   lane^8 -> row_ror:8            (j=128)
//   lane^{4,16,32} -> ds_bpermute  (j=64,256,512)
//   thread^{64,128} -> LDS         (j=1024,2048)
// ---------------------------------------------------------------------------
#define CE(SA, SB, ASC)                                                   \
    { u64 _a = r[SA], _b = r[SB];                                         \
      bool _sw = ((_a > _b) == (ASC));                                    \
      if (_sw) { r[SA] = _b; r[SB] = _a; } }

template<int CTRL>
__device__ __forceinline__ u64 dpp_xor(u64 v)
{
    u32 lo = (u32)v, hi = (u32)(v >> 32);
    u32 olo = (u32)__builtin_amdgcn_mov_dpp((int)lo, CTRL, 0xf, 0xf, true);
    u32 ohi = (u32)__builtin_amdgcn_mov_dpp((int)hi, CTRL, 0xf, 0xf, true);
    return ((u64)ohi << 32) | olo;
}

template<int K, int J>
__device__ __forceinline__ void cross_pass(u64 (&r)[16], const int t, const int lane,
                                           u64* lds, const bool up)
{
    if constexpr (J >= 1024) {
        const int m = J >> 4;                    // 64 or 128: cross-wave
        const bool wantmin = (((t & m) == 0) == up);
        __syncthreads();
#pragma unroll
        for (int s = 0; s < 16; ++s) lds[s * 256 + t] = r[s];
        __syncthreads();
        const int pt2 = t ^ m;
#pragma unroll
        for (int s = 0; s < 16; ++s) {
            u64 o = lds[s * 256 + pt2];
            r[s] = ((r[s] < o) == wantmin) ? r[s] : o;
        }
    } else if constexpr (J == 512 || J == 256 || J == 64) {
        const int m = J >> 4;                    // 32, 16, 4: bpermute
        const bool wantmin = (((t & m) == 0) == up);
        const int ba = (lane ^ m) << 2;
#pragma unroll
        for (int s = 0; s < 16; ++s) {
            u32 alo = (u32)r[s], ahi = (u32)(r[s] >> 32);
            u32 olo = (u32)__builtin_amdgcn_ds_bpermute(ba, (int)alo);
            u32 ohi = (u32)__builtin_amdgcn_ds_bpermute(ba, (int)ahi);
            u64 o = ((u64)ohi << 32) | olo;
            r[s] = ((r[s] < o) == wantmin) ? r[s] : o;
        }
    } else {
        constexpr int m    = J >> 4;             // 8, 2, 1: DPP
        constexpr int ctrl = (m == 8) ? 0x128 : (m == 2 ? 0x4E : 0xB1);
        const bool wantmin = (((t & m) == 0) == up);
#pragma unroll
        for (int s = 0; s < 16; ++s) {
            u64 o = dpp_xor<ctrl>(r[s]);
            r[s] = ((r[s] < o) == wantmin) ? r[s] : o;
        }
    }
}

template<int K>
__device__ __forceinline__ void bigstage(u64 (&r)[16], const int t, const int lane, u64* lds)
{
    const bool up = ((t & (K >> 4)) == 0);
    if constexpr (K >= 4096) cross_pass<K, 2048>(r, t, lane, lds, up);
    if constexpr (K >= 2048) cross_pass<K, 1024>(r, t, lane, lds, up);
    if constexpr (K >= 1024) cross_pass<K, 512>(r, t, lane, lds, up);
    if constexpr (K >= 512)  cross_pass<K, 256>(r, t, lane, lds, up);
    if constexpr (K >= 256)  cross_pass<K, 128>(r, t, lane, lds, up);
    if constexpr (K >= 128)  cross_pass<K, 64>(r, t, lane, lds, up);
    if constexpr (K >= 64)   cross_pass<K, 32>(r, t, lane, lds, up);
    cross_pass<K, 16>(r, t, lane, lds, up);
#pragma unroll
    for (int j2 = 8; j2 >= 1; j2 >>= 1)
#pragma unroll
        for (int s = 0; s < 16; ++s)
            if ((s & j2) == 0) { CE(s, s | j2, up) }
}

__global__ __launch_bounds__(256, 2)
void k_sortpool(const float* __restrict__ hbuf, const int* __restrict__ n_points,
                const float* __restrict__ pool_w, float* __restrict__ out)
{
    __shared__ u64 lds[4096];
    __shared__ float pw[PIECES_ + 1];
    __shared__ float red[4];

    const int t    = threadIdx.x;
    const int lane = t & 63;
    const int bc   = blockIdx.x;          // b*256 + c
    const int c    = bc & 255;

    if (t < PIECES_ + 1) pw[t] = pool_w[c * (PIECES_ + 1) + t];

    const int n  = n_points[bc >> 8];
    const int dn = (n - 1) > 1 ? (n - 1) : 1;
    const float denomf = (float)dn;

    const float* hrow = hbuf + (size_t)bc * NPTS;
    u64 r[16];
#pragma unroll
    for (int s4 = 0; s4 < 4; ++s4) {
        float4 hv = *(const float4*)&hrow[t * 16 + s4 * 4];
        float hvv[4] = {hv.x, hv.y, hv.z, hv.w};
#pragma unroll
        for (int v = 0; v < 4; ++v) {
            int i = t * 16 + s4 * 4 + v;
            float hm = (i <= dn) ? hvv[v] : __fadd_rn(hvv[v], -99999.0f);
            u32 ub = __float_as_uint(hm);
            if ((ub & 0x7FFFFFFFu) == 0) ub = 0;   // canonicalize -0 -> +0
            u32 u  = (ub & 0x80000000u) ? ~ub : (ub ^ 0x80000000u);
            r[s4 * 4 + v] = ((u64)(~u) << 32) | (u32)i;
        }
    }

    // ---- stages k = 2, 4, 8: fully compile-time ----
#pragma unroll
    for (int kk = 1; kk <= 3; ++kk) {
        const int k = 1 << kk;
#pragma unroll
        for (int j = (1 << kk) >> 1; j >= 1; j >>= 1) {
#pragma unroll
            for (int s = 0; s < 16; ++s) {
                if ((s & j) == 0) {
                    const bool asc = ((s & k) == 0);
                    CE(s, s | j, asc)
                }
            }
        }
    }

    // ---- stage k = 16: direction uniform per thread ----
    {
        const bool asc16 = ((t & 1) == 0);
#pragma unroll
        for (int j = 8; j >= 1; j >>= 1)
#pragma unroll
            for (int s = 0; s < 16; ++s)
                if ((s & j) == 0) { CE(s, s | j, asc16) }
    }

    // ---- stages k = 32..4096 ----
    bigstage<32>(r, t, lane, lds);
    bigstage<64>(r, t, lane, lds);
    bigstage<128>(r, t, lane, lds);
    bigstage<256>(r, t, lane, lds);
    bigstage<512>(r, t, lane, lds);
    bigstage<1024>(r, t, lane, lds);
    bigstage<2048>(r, t, lane, lds);
    bigstage<4096>(r, t, lane, lds);

    // ---- perm write (over the h row) + pooled partial ----
    float* permout = out + 8192 + (size_t)bc * NPTS;
    float local = 0.f;
#pragma unroll
    for (int s4 = 0; s4 < 4; ++s4) {
        float pv[4];
#pragma unroll
        for (int v = 0; v < 4; ++v) {
            int i = t * 16 + s4 * 4 + v;
            u64 key = r[s4 * 4 + v];
            pv[v] = (float)(u32)(key & 0xFFFFFFFFu);
            if (i <= dn) {
                u32 u    = ~(u32)(key >> 32);
                u32 bits = (u & 0x80000000u) ? (u ^ 0x80000000u) : ~u;
                float hs = __uint_as_float(bits);
                float ratio = (float)i / denomf;
                float index = 20.0f * ratio;
                int   ii    = (int)index;
                if (ii > PIECES_) ii = PIECES_;
                float frac  = index - (float)ii;
                int   i2    = ii + 1 < PIECES_ ? ii + 1 : PIECES_;
                float w = (1.0f - frac) * pw[ii] + frac * pw[i2];
                local += hs * w;
            }
        }
        float4 pq = make_float4(pv[0], pv[1], pv[2], pv[3]);
        *(float4*)&permout[t * 16 + s4 * 4] = pq;
    }
#pragma unroll
    for (int off = 32; off >= 1; off >>= 1)
        local += __shfl_down(local, (unsigned)off, 64);
    if ((t & 63) == 0) red[t >> 6] = local;
    __syncthreads();
    if (t == 0) out[bc] = red[0] + red[1] + red[2] + red[3];
}

// ---------------------------------------------------------------------------
// Kernel 3: y = relu(pooled @ L1^T + bl1) @ L2^T + bl2, in place over pooled.
// ---------------------------------------------------------------------------
__global__ void k_mlp(const float* __restrict__ L1, const float* __restrict__ bl1,
                      const float* __restrict__ L2, const float* __restrict__ bl2,
                      float* __restrict__ out)
{
    __shared__ float ps[DIM_];
    __shared__ float zs[DIM_];
    const int b = blockIdx.x, t = threadIdx.x;
    ps[t] = out[b * DIM_ + t];
    __syncthreads();
    float a = bl1[t];
    for (int i = 0; i < DIM_; ++i) a += L1[t * DIM_ + i] * ps[i];
    zs[t] = a > 0.f ? a : 0.f;
    __syncthreads();
    float y = bl2[t];
    for (int i = 0; i < DIM_; ++i) y += L2[t * DIM_ + i] * zs[i];
    out[b * DIM_ + t] = y;
}

// ---------------------------------------------------------------------------
extern "C" void kernel_launch(void* const* d_in, const int* in_sizes, int n_in,
                              void* d_out, int out_size, void* d_ws, size_t ws_size,
                              hipStream_t stream)
{
    (void)in_sizes; (void)n_in; (void)d_ws; (void)ws_size; (void)out_size;

    const float* x        = (const float*)d_in[0];
    const int*   n_points = (const int*)  d_in[1];
    const float* W1       = (const float*)d_in[2];
    const float* b1       = (const float*)d_in[3];
    const float* W2       = (const float*)d_in[4];
    const float* b2       = (const float*)d_in[5];
    const float* pool_w   = (const float*)d_in[6];
    const float* L1       = (const float*)d_in[7];
    const float* bl1      = (const float*)d_in[8];
    const float* L2       = (const float*)d_in[9];
    const float* bl2      = (const float*)d_in[10];

    float* out  = (float*)d_out;
    float* hbuf = out + 8192;   // stage h in the perm region

    k_h<<<dim3(NPTS / BP, DIM_ / BM, B_), 256, 0, stream>>>(x, W1, b1, W2, b2, hbuf);
    k_sortpool<<<B_ * DIM_, 256, 0, stream>>>(hbuf, n_points, pool_w, out);
    k_mlp<<<B_, 256, 0, stream>>>(L1, bl1, L2, bl2, out);
}